// Round 9
// baseline (110.608 us; speedup 1.0000x reference)
//
#include <hip/hip_runtime.h>

// VQ-VAE forward + EMA update, MI355X.
// Sizes fixed by the reference: B=64, C=D=8, H=W=64, K=512.
constexpr int Kc   = 512;
constexpr int Dc   = 8;
constexpr int HWc  = 4096;            // 64*64
constexpr int CHWc = Dc * HWc;        // 32768
constexpr int Mc   = 64 * HWc;        // 262144 vectors
constexpr int TOTALc = Mc * Dc;       // 2097152 elements of z / z_q

// 8 replica accumulators (one per XCD via blockIdx&7) to cut atomic contention.
constexpr int REP      = 8;
constexpr int RSTRIDE  = 4616;        // 512 counts + 4096 sums + 1 loss + 7 pad
constexpr int ACC_FLOATS = REP * RSTRIDE;   // 36928 floats (~148 KB)
// d_ws float layout:
//   [0 .. ACC_FLOATS)            replica accumulators (counts | sums | loss | pad) x8
//   [ACC_FLOATS .. +512)         e_sq[k]

typedef float v2f __attribute__((ext_vector_type(2)));
typedef float f4  __attribute__((ext_vector_type(4)));
typedef unsigned long long ull;
typedef ull  u64x4 __attribute__((ext_vector_type(4)));

__global__ __launch_bounds__(256) void vq_prep(const float* __restrict__ cb,
                                               float* __restrict__ ws) {
    const int tid = blockIdx.x * 256 + threadIdx.x;
    float4* w4 = (float4*)ws;
    for (int i = tid; i < ACC_FLOATS / 4; i += gridDim.x * 256)
        w4[i] = float4{0.f, 0.f, 0.f, 0.f};
    if (blockIdx.x == 0) {
        for (int k = threadIdx.x; k < Kc; k += 256) {
            float s = 0.f;
#pragma unroll
            for (int c = 0; c < Dc; ++c) {
                const float e = cb[k * Dc + c];
                s = fmaf(e, e, s);
            }
            ws[ACC_FLOATS + k] = s;
        }
    }
}

// 1024 blocks x 512 threads; block owns 256 consecutive vectors.
// 8 k-groups x 1 wave; lane l scores V=4 vectors (l,l+64,l+128,l+192) via
// v_pk_fma_f32 (codebook pair in SGPR pair from s_load_dwordx8, lo/hi
// broadcast via op_sel).
// KEY CHANGE vs the 46us r8 kernel: FORCE the 32 zz floats to stay VGPR-
// resident. Evidence: VGPR_Count was 20-32 in r0-r8 while zzA+zzB alone need
// 32 regs -> the compiler REMATERIALIZED the (provably invariant) z loads
// inside the k-loop, re-fetching z via VMEM every iteration. That hidden
// in-loop vmcnt stall + remul is the ~19us idle invariant across all load-
// path experiments (SMEM bytes / requests / DS / vector all neutral-or-worse
// while VALU-busy stayed ~27us). Fix: (a) asm-pin zz after staging (asm-
// produced values cannot be rematerialized), (b) __launch_bounds__(512,6)
// -> ~85-VGPR budget, 6 waves/SIMD, 3 blocks/CU. Math BIT-IDENTICAL to
// r0/r4/r8: a = esq[k]; a += zz[c]*e[c], c ascending; strict-< first-wins;
// groups ascending in k.
__global__ __launch_bounds__(512, 6) void vq_main(const float* __restrict__ z,
                                                  const float* __restrict__ cb,
                                                  const float* __restrict__ esq,
                                                  float* __restrict__ ws,
                                                  float* __restrict__ zq) {
    __shared__ float s_mn[8][256];         // 8 KB
    __shared__ int   s_im[8][256];         // 8 KB
    __shared__ float s_counts[Kc];         // 2 KB
    __shared__ float s_sums[Kc * Dc];      // 16 KB
    __shared__ float s_loss;

    const int t = threadIdx.x;
    for (int i = t; i < Kc; i += 512) s_counts[i] = 0.f;
    for (int i = t; i < Kc * Dc; i += 512) s_sums[i] = 0.f;
    if (t == 0) s_loss = 0.f;

    const int l = t & 63;
    // wave-uniform k-group; readfirstlane keeps codebook indices provably
    // uniform -> s_load (scalar) path for cb/esq.
    const int g  = __builtin_amdgcn_readfirstlane(t >> 6);   // 0..7
    const int k0 = g << 6;

    const int base = blockIdx.x * 256;        // 256-aligned -> one batch idx
    const int b  = base >> 12;
    const int n0 = (base & (HWc - 1)) + l;    // +64*j below never wraps 4096
    const float* zb = z + b * CHWc + n0;

    // zzA[c] = (-2*z[vec l][c], -2*z[vec l+64][c]); zzB: vecs l+128, l+192.
    v2f zzA[Dc], zzB[Dc];
#pragma unroll
    for (int c = 0; c < Dc; ++c) {
        zzA[c] = v2f{-2.0f * zb[c * HWc],       -2.0f * zb[c * HWc + 64]};
        zzB[c] = v2f{-2.0f * zb[c * HWc + 128], -2.0f * zb[c * HWc + 192]};
    }
    // Pin zz as opaque asm-defined values: blocks LLVM's invariant-load
    // rematerialization, forcing all 32 floats to stay VGPR-resident across
    // the k-loop (values unchanged — empty asm).
    asm("" : "+v"(zzA[0]), "+v"(zzA[1]), "+v"(zzA[2]), "+v"(zzA[3]),
             "+v"(zzA[4]), "+v"(zzA[5]), "+v"(zzA[6]), "+v"(zzA[7]),
             "+v"(zzB[0]), "+v"(zzB[1]), "+v"(zzB[2]), "+v"(zzB[3]),
             "+v"(zzB[4]), "+v"(zzB[5]), "+v"(zzB[6]), "+v"(zzB[7]));

    float mn0 = 3.4e38f, mn1 = 3.4e38f, mn2 = 3.4e38f, mn3 = 3.4e38f;
    int   i0 = k0, i1 = k0, i2 = k0, i3 = k0;
    // outer loop: 4 codes per iteration; one dwordx4 (esq) + 4 dwordx8 (rows)
    for (int kq = 0; kq < 16; ++kq) {
        const int kb = k0 + kq * 4;
        const f4 ev4 = *(const f4*)(esq + kb);           // s_load_dwordx4
#pragma unroll
        for (int j = 0; j < 4; ++j) {
            const int k = kb + j;
            const u64x4 row = *(const u64x4*)(cb + 8 * k);  // s_load_dwordx8
            const ull q0 = row.x, q1 = row.y, q2 = row.z, q3 = row.w;
            const float ev = ev4[j];
            const v2f vev2 = {ev, ev};
            v2f aA, aB;
            // op_sel_hi:[1,0,1] broadcasts the LOW dword of the sgpr pair
            // (e[2p]); op_sel:[0,1,0] (default op_sel_hi) broadcasts the
            // HIGH dword (e[2p+1]). First step folds the {ev,ev} addend
            // directly (same value & rounding as init-then-fma).
            asm("v_pk_fma_f32 %0, %2, %4, %5 op_sel_hi:[1,0,1]\n\t"
                "v_pk_fma_f32 %1, %3, %4, %5 op_sel_hi:[1,0,1]\n\t"
                "v_pk_fma_f32 %0, %6, %4, %0 op_sel:[0,1,0]\n\t"
                "v_pk_fma_f32 %1, %7, %4, %1 op_sel:[0,1,0]"
                : "=&v"(aA), "=&v"(aB)
                : "v"(zzA[0]), "v"(zzB[0]), "s"(q0), "v"(vev2),
                  "v"(zzA[1]), "v"(zzB[1]));
#define PKSTEP(Q, P0, P1)                                              \
            asm("v_pk_fma_f32 %0, %2, %4, %0 op_sel_hi:[1,0,1]\n\t"    \
                "v_pk_fma_f32 %1, %3, %4, %1 op_sel_hi:[1,0,1]\n\t"    \
                "v_pk_fma_f32 %0, %5, %4, %0 op_sel:[0,1,0]\n\t"       \
                "v_pk_fma_f32 %1, %6, %4, %1 op_sel:[0,1,0]"           \
                : "+v"(aA), "+v"(aB)                                   \
                : "v"(zzA[P0]), "v"(zzB[P0]), "s"(Q), "v"(zzA[P1]), "v"(zzB[P1]))
            PKSTEP(q1, 2, 3);
            PKSTEP(q2, 4, 5);
            PKSTEP(q3, 6, 7);
#undef PKSTEP
            const float a0 = aA.x, a1 = aA.y, a2 = aB.x, a3 = aB.y;
            bool c;
            c = a0 < mn0; mn0 = c ? a0 : mn0; i0 = c ? k : i0;
            c = a1 < mn1; mn1 = c ? a1 : mn1; i1 = c ? k : i1;
            c = a2 < mn2; mn2 = c ? a2 : mn2; i2 = c ? k : i2;
            c = a3 < mn3; mn3 = c ? a3 : mn3; i3 = c ? k : i3;
        }
    }
    s_mn[g][l]       = mn0;  s_im[g][l]       = i0;
    s_mn[g][l +  64] = mn1;  s_im[g][l +  64] = i1;
    s_mn[g][l + 128] = mn2;  s_im[g][l + 128] = i2;
    s_mn[g][l + 192] = mn3;  s_im[g][l + 192] = i3;
    __syncthreads();

    if (t < 256) {
        const int v = t;                      // block-local vector id
        float mn = s_mn[0][v];
        int   im = s_im[0][v];
#pragma unroll
        for (int gg = 1; gg < 8; ++gg) {
            const float m2 = s_mn[gg][v];     // groups ascending in k:
            const int   j2 = s_im[gg][v];     // strict < keeps first index
            const bool  c2 = m2 < mn;
            mn = c2 ? m2 : mn;
            im = c2 ? j2 : im;
        }

        // Gather old-codebook row (16 KB table, L1-hot; 32B/lane).
        const float4* cb4 = (const float4*)cb;
        const float4 qa = cb4[im * 2], qb = cb4[im * 2 + 1];
        const float q[Dc] = {qa.x, qa.y, qa.z, qa.w, qb.x, qb.y, qb.z, qb.w};

        const int nv = (base & (HWc - 1)) + v;
        const float* zv = z + b * CHWc + nv;  // re-read z (L1/L2-hot)
        float* zqv = zq + b * CHWc + nv;
        float lsum = 0.f;
        float zr[Dc];
#pragma unroll
        for (int c = 0; c < Dc; ++c) {
            zr[c] = zv[c * HWc];
            zqv[c * HWc] = q[c];              // coalesced stores
            const float d = q[c] - zr[c];
            lsum = fmaf(d, d, lsum);
        }

        // Per-block LDS histogram (ds_add_f32) — coalesces same-index hits.
        unsafeAtomicAdd(&s_counts[im], 1.0f);
#pragma unroll
        for (int c = 0; c < Dc; ++c)
            unsafeAtomicAdd(&s_sums[im * Dc + c], zr[c]);
        unsafeAtomicAdd(&s_loss, lsum);
    }
    __syncthreads();

    // Flush non-zero bins to this block's replica accumulator (all 512 thr).
    float* acc = ws + (blockIdx.x & (REP - 1)) * RSTRIDE;
    for (int i = t; i < Kc; i += 512) {
        const float val = s_counts[i];
        if (val != 0.f) unsafeAtomicAdd(&acc[i], val);
    }
    for (int i = t; i < Kc * Dc; i += 512) {
        const float val = s_sums[i];
        if (val != 0.f) unsafeAtomicAdd(&acc[512 + i], val);
    }
    if (t == 0) unsafeAtomicAdd(&acc[4608], s_loss);
}

// 9 blocks: every block redundantly recomputes the (cheap) counts/cs phase;
// block 0 writes cs + loss, blocks 1..8 each handle 512 of the 4096 K*D
// elements.
__global__ __launch_bounds__(512) void vq_final(const float* __restrict__ ws,
                                                const float* __restrict__ ema_cs,
                                                const float* __restrict__ ema_w,
                                                float* __restrict__ out) {
    constexpr float DEC  = 0.99f;
    constexpr float OMD  = (float)(1.0 - 0.99);      // matches jnp f32 cast
    constexpr float EPSf = 1e-5f;
    constexpr float KEPS = (float)(512 * 1e-5);      // 0.00512
    __shared__ float red[512];
    __shared__ float s_cs[512];

    const int t = threadIdx.x;
    // counts: lane-consecutive reads per replica (coalesced)
    float cnt = 0.f;
#pragma unroll
    for (int r = 0; r < REP; ++r) cnt += ws[r * RSTRIDE + t];
    const float ncs = ema_cs[t] * DEC + cnt * OMD;
    red[t] = ncs;
    __syncthreads();
    for (int s = 256; s > 0; s >>= 1) {
        if (t < s) red[t] += red[t + s];
        __syncthreads();
    }
    const float n  = red[0];
    const float cs = (ncs + EPSf) / (n + KEPS) * n;
    s_cs[t] = cs;

    float* out_loss = out + TOTALc;          // [1]
    float* out_cb   = out + TOTALc + 1;      // [K*D]
    float* out_cs   = out_cb + Kc * Dc;      // [K]
    float* out_nw   = out_cs + Kc;           // [K*D]

    __syncthreads();

    const int blk = blockIdx.x;
    if (blk == 0) {
        out_cs[t] = cs;
        if (t == 0) {
            float ls = 0.f;
#pragma unroll
            for (int r = 0; r < REP; ++r) ls += ws[r * RSTRIDE + 4608];
            out_loss[0] = ls * (1.0f / 2097152.0f);  // /2^21 exact
        }
    } else {
        const int e = (blk - 1) * 512 + t;   // one element per thread
        float sm = 0.f;
#pragma unroll
        for (int r = 0; r < REP; ++r) sm += ws[r * RSTRIDE + 512 + e];
        const float nw = ema_w[e] * DEC + sm * OMD;
        out_nw[e] = nw;
        out_cb[e] = nw / s_cs[e >> 3];
    }
}

extern "C" void kernel_launch(void* const* d_in, const int* in_sizes, int n_in,
                              void* d_out, int out_size, void* d_ws, size_t ws_size,
                              hipStream_t stream) {
    const float* z      = (const float*)d_in[0];
    const float* cb     = (const float*)d_in[1];
    const float* ema_cs = (const float*)d_in[2];
    const float* ema_w  = (const float*)d_in[3];
    float* out = (float*)d_out;
    float* ws  = (float*)d_ws;

    vq_prep<<<32, 256, 0, stream>>>(cb, ws);
    vq_main<<<Mc / 256, 512, 0, stream>>>(z, cb, ws + ACC_FLOATS, ws, out);
    vq_final<<<9, 512, 0, stream>>>(ws, ema_cs, ema_w, out);
}

// Round 11
// 107.064 us; speedup vs baseline: 1.0331x; 1.0331x over previous
//
#include <hip/hip_runtime.h>

// VQ-VAE forward + EMA update, MI355X.
// Sizes fixed by the reference: B=64, C=D=8, H=W=64, K=512.
constexpr int Kc   = 512;
constexpr int Dc   = 8;
constexpr int HWc  = 4096;            // 64*64
constexpr int CHWc = Dc * HWc;        // 32768
constexpr int Mc   = 64 * HWc;        // 262144 vectors
constexpr int TOTALc = Mc * Dc;       // 2097152 elements of z / z_q

// 8 replica accumulators (one per XCD via blockIdx&7) to cut atomic contention.
constexpr int REP      = 8;
constexpr int RSTRIDE  = 4616;        // 512 counts + 4096 sums + 1 loss + 7 pad
constexpr int ACC_FLOATS = REP * RSTRIDE;   // 36928 floats (~148 KB)
// d_ws float layout:
//   [0 .. ACC_FLOATS)            replica accumulators (counts | sums | loss | pad) x8
//   [ACC_FLOATS .. +512)         e_sq[k]

typedef float v2f __attribute__((ext_vector_type(2)));
typedef float f4  __attribute__((ext_vector_type(4)));
typedef unsigned long long ull;
typedef ull  u64x4 __attribute__((ext_vector_type(4)));

__global__ __launch_bounds__(256) void vq_prep(const float* __restrict__ cb,
                                               float* __restrict__ ws) {
    const int tid = blockIdx.x * 256 + threadIdx.x;
    float4* w4 = (float4*)ws;
    for (int i = tid; i < ACC_FLOATS / 4; i += gridDim.x * 256)
        w4[i] = float4{0.f, 0.f, 0.f, 0.f};
    if (blockIdx.x == 0) {
        for (int k = threadIdx.x; k < Kc; k += 256) {
            float s = 0.f;
#pragma unroll
            for (int c = 0; c < Dc; ++c) {
                const float e = cb[k * Dc + c];
                s = fmaf(e, e, s);
            }
            ws[ACC_FLOATS + k] = s;
        }
    }
}

// 1024 blocks x 512 threads; block owns 256 consecutive vectors.
// 8 k-groups x 1 wave; lane l scores V=4 vectors (l,l+64,l+128,l+192) via
// v_pk_fma_f32 (codebook pair in SGPR pair, lo/hi broadcast via op_sel).
// KEY CHANGE vs the 46us r8 kernel: SOFTWARE-PIPELINED SCALAR PREFETCH.
// Convoy model (from r0-r9 data): per 4-code iter a wave issues ~368 VALU-cyc
// then drains lgkmcnt(0) for THAT iter's s_loads (SMEM is out-of-order ->
// full drain; next iter's loads issue only after the branch). Single-wave
// duty = 368/(368+L). Measured VALUBusy 59% == single-wave duty (L~255cyc)
// even though 8 waves/SIMD demand 470% -> all 8 waves stall in LOCKSTEP
// (self-stabilizing convoy: laggards catch up on the free pipe). Explains
// every null result: bytes(r4), requests(r8), occupancy(r9), DS(r7 at its
// own 49% duty). Fix: prefetch iter kq+1's rows+esq into SGPRs BEFORE
// computing iter kq -> the drain at iter kq+1's top waits on ~368-cyc-old
// loads -> wait~0 -> duty~100% -> pipe saturates. Ping-pong via loop-carried
// SGPR values + unroll 2; last iter clamps the prefetch index (branchless).
// Math BIT-IDENTICAL to r0/r4/r8: a = esq[k]; a += zz[c]*e[c], c ascending;
// strict-< first-index-wins; groups ascending in k.
__global__ __launch_bounds__(512, 8) void vq_main(const float* __restrict__ z,
                                                  const float* __restrict__ cb,
                                                  const float* __restrict__ esq,
                                                  float* __restrict__ ws,
                                                  float* __restrict__ zq) {
    __shared__ float s_mn[8][256];         // 8 KB
    __shared__ int   s_im[8][256];         // 8 KB
    __shared__ float s_counts[Kc];         // 2 KB
    __shared__ float s_sums[Kc * Dc];      // 16 KB
    __shared__ float s_loss;

    const int t = threadIdx.x;
    for (int i = t; i < Kc; i += 512) s_counts[i] = 0.f;
    for (int i = t; i < Kc * Dc; i += 512) s_sums[i] = 0.f;
    if (t == 0) s_loss = 0.f;

    const int l = t & 63;
    // wave-uniform k-group; readfirstlane keeps codebook indices provably
    // uniform -> s_load (scalar) path for cb/esq.
    const int g  = __builtin_amdgcn_readfirstlane(t >> 6);   // 0..7
    const int k0 = g << 6;

    const int base = blockIdx.x * 256;        // 256-aligned -> one batch idx
    const int b  = base >> 12;
    const int n0 = (base & (HWc - 1)) + l;    // +64*j below never wraps 4096
    const float* zb = z + b * CHWc + n0;

    // zzA[c] = (-2*z[vec l][c], -2*z[vec l+64][c]); zzB: vecs l+128, l+192.
    v2f zzA[Dc], zzB[Dc];
#pragma unroll
    for (int c = 0; c < Dc; ++c) {
        zzA[c] = v2f{-2.0f * zb[c * HWc],       -2.0f * zb[c * HWc + 64]};
        zzB[c] = v2f{-2.0f * zb[c * HWc + 128], -2.0f * zb[c * HWc + 192]};
    }

    const float* cbg = cb + (k0 << 3);        // uniform: this group's 64 rows
    const float* eqg = esq + k0;

    // ---- prologue: load iteration 0's rows + esq into SGPRs ----
    u64x4 nr0 = *(const u64x4*)(cbg + 0);     // s_load_dwordx8 (row 4*0+0)
    u64x4 nr1 = *(const u64x4*)(cbg + 8);
    u64x4 nr2 = *(const u64x4*)(cbg + 16);
    u64x4 nr3 = *(const u64x4*)(cbg + 24);
    f4    nev = *(const f4*)(eqg);            // s_load_dwordx4

    float mn0 = 3.4e38f, mn1 = 3.4e38f, mn2 = 3.4e38f, mn3 = 3.4e38f;
    int   i0 = k0, i1 = k0, i2 = k0, i3 = k0;
#pragma unroll 2
    for (int kq = 0; kq < 16; ++kq) {
        // consume the prefetched set (lgkmcnt drain here waits on loads that
        // have had a full compute phase in flight -> ~0 stall)
        const u64x4 r0 = nr0, r1 = nr1, r2 = nr2, r3 = nr3;
        const f4 ev4 = nev;

        // issue NEXT iteration's loads before the 368-cyc compute phase
        const int kqn = (kq + 1 < 16) ? kq + 1 : 15;   // clamped, branchless
        nr0 = *(const u64x4*)(cbg + 32 * kqn + 0);
        nr1 = *(const u64x4*)(cbg + 32 * kqn + 8);
        nr2 = *(const u64x4*)(cbg + 32 * kqn + 16);
        nr3 = *(const u64x4*)(cbg + 32 * kqn + 24);
        nev = *(const f4*)(eqg + 4 * kqn);

        const int kb = k0 + kq * 4;
#pragma unroll
        for (int j = 0; j < 4; ++j) {
            const int k = kb + j;
            const u64x4 row = (j == 0) ? r0 : (j == 1) ? r1 : (j == 2) ? r2 : r3;
            const ull q0 = row.x, q1 = row.y, q2 = row.z, q3 = row.w;
            const float ev = ev4[j];
            const v2f vev2 = {ev, ev};
            v2f aA, aB;
            // op_sel_hi:[1,0,1] broadcasts the LOW dword of the sgpr pair
            // (e[2p]); op_sel:[0,1,0] (default op_sel_hi) broadcasts the
            // HIGH dword (e[2p+1]). First step folds the {ev,ev} addend
            // directly (same value & rounding as init-then-fma).
            asm("v_pk_fma_f32 %0, %2, %4, %5 op_sel_hi:[1,0,1]\n\t"
                "v_pk_fma_f32 %1, %3, %4, %5 op_sel_hi:[1,0,1]\n\t"
                "v_pk_fma_f32 %0, %6, %4, %0 op_sel:[0,1,0]\n\t"
                "v_pk_fma_f32 %1, %7, %4, %1 op_sel:[0,1,0]"
                : "=&v"(aA), "=&v"(aB)
                : "v"(zzA[0]), "v"(zzB[0]), "s"(q0), "v"(vev2),
                  "v"(zzA[1]), "v"(zzB[1]));
#define PKSTEP(Q, P0, P1)                                              \
            asm("v_pk_fma_f32 %0, %2, %4, %0 op_sel_hi:[1,0,1]\n\t"    \
                "v_pk_fma_f32 %1, %3, %4, %1 op_sel_hi:[1,0,1]\n\t"    \
                "v_pk_fma_f32 %0, %5, %4, %0 op_sel:[0,1,0]\n\t"       \
                "v_pk_fma_f32 %1, %6, %4, %1 op_sel:[0,1,0]"           \
                : "+v"(aA), "+v"(aB)                                   \
                : "v"(zzA[P0]), "v"(zzB[P0]), "s"(Q), "v"(zzA[P1]), "v"(zzB[P1]))
            PKSTEP(q1, 2, 3);
            PKSTEP(q2, 4, 5);
            PKSTEP(q3, 6, 7);
#undef PKSTEP
            const float a0 = aA.x, a1 = aA.y, a2 = aB.x, a3 = aB.y;
            bool c;
            c = a0 < mn0; mn0 = c ? a0 : mn0; i0 = c ? k : i0;
            c = a1 < mn1; mn1 = c ? a1 : mn1; i1 = c ? k : i1;
            c = a2 < mn2; mn2 = c ? a2 : mn2; i2 = c ? k : i2;
            c = a3 < mn3; mn3 = c ? a3 : mn3; i3 = c ? k : i3;
        }
    }
    s_mn[g][l]       = mn0;  s_im[g][l]       = i0;
    s_mn[g][l +  64] = mn1;  s_im[g][l +  64] = i1;
    s_mn[g][l + 128] = mn2;  s_im[g][l + 128] = i2;
    s_mn[g][l + 192] = mn3;  s_im[g][l + 192] = i3;
    __syncthreads();

    if (t < 256) {
        const int v = t;                      // block-local vector id
        float mn = s_mn[0][v];
        int   im = s_im[0][v];
#pragma unroll
        for (int gg = 1; gg < 8; ++gg) {
            const float m2 = s_mn[gg][v];     // groups ascending in k:
            const int   j2 = s_im[gg][v];     // strict < keeps first index
            const bool  c2 = m2 < mn;
            mn = c2 ? m2 : mn;
            im = c2 ? j2 : im;
        }

        // Gather old-codebook row (16 KB table, L1-hot; 32B/lane).
        const float4* cb4 = (const float4*)cb;
        const float4 qa = cb4[im * 2], qb = cb4[im * 2 + 1];
        const float q[Dc] = {qa.x, qa.y, qa.z, qa.w, qb.x, qb.y, qb.z, qb.w};

        const int nv = (base & (HWc - 1)) + v;
        const float* zv = z + b * CHWc + nv;  // re-read z (L1/L2-hot)
        float* zqv = zq + b * CHWc + nv;
        float lsum = 0.f;
        float zr[Dc];
#pragma unroll
        for (int c = 0; c < Dc; ++c) {
            zr[c] = zv[c * HWc];
            zqv[c * HWc] = q[c];              // coalesced stores
            const float d = q[c] - zr[c];
            lsum = fmaf(d, d, lsum);
        }

        // Per-block LDS histogram (ds_add_f32) — coalesces same-index hits.
        unsafeAtomicAdd(&s_counts[im], 1.0f);
#pragma unroll
        for (int c = 0; c < Dc; ++c)
            unsafeAtomicAdd(&s_sums[im * Dc + c], zr[c]);
        unsafeAtomicAdd(&s_loss, lsum);
    }
    __syncthreads();

    // Flush non-zero bins to this block's replica accumulator (all 512 thr).
    float* acc = ws + (blockIdx.x & (REP - 1)) * RSTRIDE;
    for (int i = t; i < Kc; i += 512) {
        const float val = s_counts[i];
        if (val != 0.f) unsafeAtomicAdd(&acc[i], val);
    }
    for (int i = t; i < Kc * Dc; i += 512) {
        const float val = s_sums[i];
        if (val != 0.f) unsafeAtomicAdd(&acc[512 + i], val);
    }
    if (t == 0) unsafeAtomicAdd(&acc[4608], s_loss);
}

// 9 blocks: every block redundantly recomputes the (cheap) counts/cs phase;
// block 0 writes cs + loss, blocks 1..8 each handle 512 of the 4096 K*D
// elements.
__global__ __launch_bounds__(512) void vq_final(const float* __restrict__ ws,
                                                const float* __restrict__ ema_cs,
                                                const float* __restrict__ ema_w,
                                                float* __restrict__ out) {
    constexpr float DEC  = 0.99f;
    constexpr float OMD  = (float)(1.0 - 0.99);      // matches jnp f32 cast
    constexpr float EPSf = 1e-5f;
    constexpr float KEPS = (float)(512 * 1e-5);      // 0.00512
    __shared__ float red[512];
    __shared__ float s_cs[512];

    const int t = threadIdx.x;
    // counts: lane-consecutive reads per replica (coalesced)
    float cnt = 0.f;
#pragma unroll
    for (int r = 0; r < REP; ++r) cnt += ws[r * RSTRIDE + t];
    const float ncs = ema_cs[t] * DEC + cnt * OMD;
    red[t] = ncs;
    __syncthreads();
    for (int s = 256; s > 0; s >>= 1) {
        if (t < s) red[t] += red[t + s];
        __syncthreads();
    }
    const float n  = red[0];
    const float cs = (ncs + EPSf) / (n + KEPS) * n;
    s_cs[t] = cs;

    float* out_loss = out + TOTALc;          // [1]
    float* out_cb   = out + TOTALc + 1;      // [K*D]
    float* out_cs   = out_cb + Kc * Dc;      // [K]
    float* out_nw   = out_cs + Kc;           // [K*D]

    __syncthreads();

    const int blk = blockIdx.x;
    if (blk == 0) {
        out_cs[t] = cs;
        if (t == 0) {
            float ls = 0.f;
#pragma unroll
            for (int r = 0; r < REP; ++r) ls += ws[r * RSTRIDE + 4608];
            out_loss[0] = ls * (1.0f / 2097152.0f);  // /2^21 exact
        }
    } else {
        const int e = (blk - 1) * 512 + t;   // one element per thread
        float sm = 0.f;
#pragma unroll
        for (int r = 0; r < REP; ++r) sm += ws[r * RSTRIDE + 512 + e];
        const float nw = ema_w[e] * DEC + sm * OMD;
        out_nw[e] = nw;
        out_cb[e] = nw / s_cs[e >> 3];
    }
}

extern "C" void kernel_launch(void* const* d_in, const int* in_sizes, int n_in,
                              void* d_out, int out_size, void* d_ws, size_t ws_size,
                              hipStream_t stream) {
    const float* z      = (const float*)d_in[0];
    const float* cb     = (const float*)d_in[1];
    const float* ema_cs = (const float*)d_in[2];
    const float* ema_w  = (const float*)d_in[3];
    float* out = (float*)d_out;
    float* ws  = (float*)d_ws;

    vq_prep<<<32, 256, 0, stream>>>(cb, ws);
    vq_main<<<Mc / 256, 512, 0, stream>>>(z, cb, ws + ACC_FLOATS, ws, out);
    vq_final<<<9, 512, 0, stream>>>(ws, ema_cs, ema_w, out);
}